// Round 14
// baseline (209.616 us; speedup 1.0000x reference)
//
#include <hip/hip_runtime.h>

constexpr int IN_DIM = 128;
constexpr int BSHIFT = 7;     // 128 nodes per bucket
constexpr int G_SORT = 256;   // blocks in the counting-sort passes
// NOTE: requires n <= 2^25 (src packs in 25 bits), n <= 1024<<BSHIFT (LDS hist),
// and NB <= 1024 (single-block bucket scan); n=100000 ok.

typedef float    f32x4  __attribute__((ext_vector_type(4)));
typedef unsigned u32x4  __attribute__((ext_vector_type(4)));
typedef short    bf16x8 __attribute__((ext_vector_type(8)));

// bf16 helpers: storage-only compression (accumulate in fp32)
__device__ inline unsigned pk_bf16(float a, float b) {  // RTNE pack of 2 floats
  unsigned ua = __float_as_uint(a), ub = __float_as_uint(b);
  ua += 0x7fff + ((ua >> 16) & 1);
  ub += 0x7fff + ((ub >> 16) & 1);
  return (ua >> 16) | (ub & 0xffff0000u);
}
__device__ inline unsigned short bf16_1(float a) {
  unsigned u = __float_as_uint(a);
  u += 0x7fff + ((u >> 16) & 1);
  return (unsigned short)(u >> 16);
}
__device__ inline float bf_lo(unsigned u) { return __uint_as_float(u << 16); }
__device__ inline float bf_hi(unsigned u) { return __uint_as_float(u & 0xffff0000u); }
__device__ inline bf16x8 as_bf16x8(uint4 v) { bf16x8 r; __builtin_memcpy(&r, &v, 16); return r; }

// ---------- k1: grid-fused {edge-bucket histogram | x fp32 -> bf16 convert} ----------
__global__ __launch_bounds__(256)
void hist_cvt_k(const int* __restrict__ ei, int E, int K, int* __restrict__ hist,
                const float* __restrict__ x, unsigned short* __restrict__ xs,
                long long nx8) {
  if (blockIdx.x < G_SORT) {
    __shared__ int lh[1024];
    for (int i = threadIdx.x; i < K; i += 256) lh[i] = 0;
    __syncthreads();
    int C = (E + G_SORT - 1) / G_SORT;
    int beg = blockIdx.x * C;
    int end = min(E, beg + C);
    for (int i = beg + threadIdx.x; i < end; i += 256)
      atomicAdd(&lh[__builtin_nontemporal_load(&ei[E + i]) >> BSHIFT], 1);
    __syncthreads();
    for (int i = threadIdx.x; i < K; i += 256) hist[blockIdx.x * K + i] = lh[i];
  } else {
    long long t = (long long)(blockIdx.x - G_SORT) * 256 + threadIdx.x;
    long long stride = (long long)(gridDim.x - G_SORT) * 256;
    for (; t < nx8; t += stride) {
      const f32x4* xp = (const f32x4*)&x[t * 8];
      f32x4 a = __builtin_nontemporal_load(xp);        // x read once
      f32x4 b = __builtin_nontemporal_load(xp + 1);
      uint4 p;
      p.x = pk_bf16(a.x, a.y); p.y = pk_bf16(a.z, a.w);
      p.z = pk_bf16(b.x, b.y); p.w = pk_bf16(b.z, b.w);
      *(uint4*)&xs[t * 8] = p;                          // xs reused by gather: keep cached
    }
  }
}

// ---------- k2: column-scan hist over blocks; emit bucket totals ----------
__global__ __launch_bounds__(G_SORT)
void hsum_k(int* __restrict__ hist, int K, int* __restrict__ btot) {
  __shared__ int sd[G_SORT];
  int k = blockIdx.x;
  int v = hist[threadIdx.x * K + k];
  sd[threadIdx.x] = v;
  __syncthreads();
#pragma unroll
  for (int ofs = 1; ofs < G_SORT; ofs <<= 1) {
    int t = (threadIdx.x >= ofs) ? sd[threadIdx.x - ofs] : 0;
    __syncthreads();
    sd[threadIdx.x] += t;
    __syncthreads();
  }
  hist[threadIdx.x * K + k] = sd[threadIdx.x] - v;       // exclusive within bucket
  if (threadIdx.x == G_SORT - 1) btot[k] = sd[threadIdx.x];  // bucket total
}

// ---------- k3: single-block exclusive scan of bucket totals -> bkbase ----------
__global__ __launch_bounds__(1024)
void bscan_k(const int* __restrict__ btot, int NB, int* __restrict__ bkbase,
             int* __restrict__ off, int n, int E) {
  __shared__ int sd[1024];
  int v = (threadIdx.x < NB) ? btot[threadIdx.x] : 0;
  sd[threadIdx.x] = v;
  __syncthreads();
#pragma unroll
  for (int ofs = 1; ofs < 1024; ofs <<= 1) {
    int t = (threadIdx.x >= ofs) ? sd[threadIdx.x - ofs] : 0;
    __syncthreads();
    sd[threadIdx.x] += t;
    __syncthreads();
  }
  if (threadIdx.x < NB) bkbase[threadIdx.x] = sd[threadIdx.x] - v;  // exclusive
  if (threadIdx.x == 0) { bkbase[NB] = E; off[n] = E; }
}

// ---------- k4: place packed (d_local,src) at reserved positions ----------
__global__ __launch_bounds__(256)
void fillc_k(const int* __restrict__ ei, int E, int K, const int* __restrict__ hist,
             const int* __restrict__ bkbase, unsigned* __restrict__ ent) {
  __shared__ int lcur[1024];
  for (int i = threadIdx.x; i < K; i += 256)
    lcur[i] = bkbase[i] + hist[blockIdx.x * K + i];
  __syncthreads();
  int C = (E + gridDim.x - 1) / gridDim.x;
  int beg = blockIdx.x * C;
  int end = min(E, beg + C);
  for (int i = beg + threadIdx.x; i < end; i += 256) {
    int s = __builtin_nontemporal_load(&ei[i]);        // ei read-once here
    int d = __builtin_nontemporal_load(&ei[E + i]);
    int pos = atomicAdd(&lcur[d >> BSHIFT], 1);
    ent[pos] = ((unsigned)(d & ((1 << BSHIFT) - 1)) << 25) | (unsigned)s;  // re-read soon: cached
  }
}

// ---------- k5: per-bucket -> node-exact CSR; derive off/dinv as by-products ----------
__global__ __launch_bounds__(256)
void fill2_k(const int* __restrict__ bkbase, const unsigned* __restrict__ ent,
             int* __restrict__ ssrc, int* __restrict__ off, float* __restrict__ dinv,
             int n) {
  constexpr int BK = 1 << BSHIFT;  // 128
  __shared__ int lcnt[BK];
  __shared__ int lbase[BK];
  __shared__ int sd[BK];
  const int tid = threadIdx.x;
  int node0 = blockIdx.x << BSHIFT;
  int nn = min(BK, n - node0);
  int beg = bkbase[blockIdx.x], end = bkbase[blockIdx.x + 1];

  if (tid < BK) lcnt[tid] = 0;
  __syncthreads();
  for (int i = beg + tid; i < end; i += 256)
    atomicAdd(&lcnt[ent[i] >> 25], 1);
  __syncthreads();
  int v = (tid < BK) ? lcnt[tid] : 0;
  if (tid < BK) sd[tid] = v;
  __syncthreads();
#pragma unroll
  for (int ofs = 1; ofs < BK; ofs <<= 1) {
    int t = 0;
    if (tid < BK && tid >= ofs) t = sd[tid - ofs];
    __syncthreads();
    if (tid < BK) sd[tid] += t;
    __syncthreads();
  }
  if (tid < BK) {
    int base = beg + sd[tid] - v;
    lbase[tid] = base;
    lcnt[tid] = 0;
    if (tid < nn) {
      off[node0 + tid] = base;
      dinv[node0 + tid] = rsqrtf((float)v + 1.0f);  // +1 self-loop
    }
  }
  __syncthreads();
  for (int i = beg + tid; i < end; i += 256) {
    unsigned p = ent[i];
    int dl = (int)(p >> 25);
    int s  = (int)(p & ((1u << 25) - 1));
    int pos = lbase[dl] + atomicAdd(&lcnt[dl], 1);
    ssrc[pos] = s;
  }
}

// ---------- k6: normalized input aggregation ----------
// Z[d] = bf16( dinv_d * ( dinv_d*xs[d] + sum_e dinv_{s_e}*xs[s_e] ) )   [= row of A_hat @ x]
__global__ __launch_bounds__(256)
void aggx_k(const int* __restrict__ off, const int* __restrict__ ssrc,
            const uint4* __restrict__ XSv, const float* __restrict__ dinv,
            unsigned short* __restrict__ Z, int n) {
  constexpr int TPR = 16;   // 16 lanes x 16B = 256B row
  constexpr int RPB = 16;
  const int lane = threadIdx.x & 15;
  const int r    = threadIdx.x >> 4;
  const int c8   = lane * 8;

  for (int d = blockIdx.x * RPB + r; d < n; d += gridDim.x * RPB) {
    int beg = off[d], end = off[d + 1];
    float dd = dinv[d];
    float acc[8];
    {
      uint4 g = XSv[(long long)d * TPR + lane];  // self-loop term * dinv_d
      acc[0] = dd * bf_lo(g.x); acc[1] = dd * bf_hi(g.x);
      acc[2] = dd * bf_lo(g.y); acc[3] = dd * bf_hi(g.y);
      acc[4] = dd * bf_lo(g.z); acc[5] = dd * bf_hi(g.z);
      acc[6] = dd * bf_lo(g.w); acc[7] = dd * bf_hi(g.w);
    }
    int e = beg;
    for (; e + 4 <= end; e += 4) {  // 4 independent gathers in flight
      int s0 = __builtin_nontemporal_load(&ssrc[e]);
      int s1 = __builtin_nontemporal_load(&ssrc[e + 1]);
      int s2 = __builtin_nontemporal_load(&ssrc[e + 2]);
      int s3 = __builtin_nontemporal_load(&ssrc[e + 3]);
      float w0 = dinv[s0], w1 = dinv[s1], w2 = dinv[s2], w3 = dinv[s3];
      uint4 g0 = XSv[(long long)s0 * TPR + lane];
      uint4 g1 = XSv[(long long)s1 * TPR + lane];
      uint4 g2 = XSv[(long long)s2 * TPR + lane];
      uint4 g3 = XSv[(long long)s3 * TPR + lane];
      acc[0] += w0 * bf_lo(g0.x) + w1 * bf_lo(g1.x) + w2 * bf_lo(g2.x) + w3 * bf_lo(g3.x);
      acc[1] += w0 * bf_hi(g0.x) + w1 * bf_hi(g1.x) + w2 * bf_hi(g2.x) + w3 * bf_hi(g3.x);
      acc[2] += w0 * bf_lo(g0.y) + w1 * bf_lo(g1.y) + w2 * bf_lo(g2.y) + w3 * bf_lo(g3.y);
      acc[3] += w0 * bf_hi(g0.y) + w1 * bf_hi(g1.y) + w2 * bf_hi(g2.y) + w3 * bf_hi(g3.y);
      acc[4] += w0 * bf_lo(g0.z) + w1 * bf_lo(g1.z) + w2 * bf_lo(g2.z) + w3 * bf_lo(g3.z);
      acc[5] += w0 * bf_hi(g0.z) + w1 * bf_hi(g1.z) + w2 * bf_hi(g2.z) + w3 * bf_hi(g3.z);
      acc[6] += w0 * bf_lo(g0.w) + w1 * bf_lo(g1.w) + w2 * bf_lo(g2.w) + w3 * bf_lo(g3.w);
      acc[7] += w0 * bf_hi(g0.w) + w1 * bf_hi(g1.w) + w2 * bf_hi(g2.w) + w3 * bf_hi(g3.w);
    }
    for (; e < end; ++e) {
      int s = ssrc[e];
      float w = dinv[s];
      uint4 g = XSv[(long long)s * TPR + lane];
      acc[0] += w * bf_lo(g.x); acc[1] += w * bf_hi(g.x);
      acc[2] += w * bf_lo(g.y); acc[3] += w * bf_hi(g.y);
      acc[4] += w * bf_lo(g.z); acc[5] += w * bf_hi(g.z);
      acc[6] += w * bf_lo(g.w); acc[7] += w * bf_hi(g.w);
    }
    u32x4 p;
    p.x = pk_bf16(dd * acc[0], dd * acc[1]);
    p.y = pk_bf16(dd * acc[2], dd * acc[3]);
    p.z = pk_bf16(dd * acc[4], dd * acc[5]);
    p.w = pk_bf16(dd * acc[6], dd * acc[7]);
    __builtin_nontemporal_store(p, (u32x4*)&Z[(long long)d * 128 + c8]);  // write-once: don't evict xs
  }
}

// ---------- k7: fused double matmul ----------
// per 64-row tile: x1 = relu(Z @ W1 + b1) (LDS, bf16); H2 = dinv * (x1 @ W2) (bf16 out)
__global__ __launch_bounds__(256)
void mm12_k(const unsigned short* __restrict__ Z, const float* __restrict__ W1,
            const float* __restrict__ b1, const float* __restrict__ W2,
            const float* __restrict__ dinv, unsigned short* __restrict__ H2,
            int n, int ntiles) {
  constexpr int KP = 136;  // padded K row stride in bf16 (272B)
  __shared__ unsigned short W1t[128 * KP];  // 34.8 KB  W1^T: [c][k]
  __shared__ unsigned short W2t[64 * KP];   // 17.4 KB  W2^T: [c][k]
  __shared__ unsigned short T[64 * KP];     // 17.4 KB  Z tile, then x1 tile

  const int tid = threadIdx.x;
  for (int i = tid; i < 128 * 128; i += 256) {
    int k = i >> 7, c = i & 127;
    W1t[c * KP + k] = bf16_1(W1[i]);
  }
  for (int i = tid; i < 128 * 64; i += 256) {
    int k = i / 64, c = i % 64;
    W2t[c * KP + k] = bf16_1(W2[i]);
  }
  const int wv = tid >> 6, l = tid & 63, l16 = l & 15, lg = l >> 4;
  const int rb = wv * 16 + lg * 4;

  for (int t = blockIdx.x; t < ntiles; t += gridDim.x) {
    int row0 = t * 64;
    __syncthreads();  // W staging (first iter) / prev-tile readers done
    for (int i = tid; i < 64 * 16; i += 256) {
      int r = i >> 4, kg8 = i & 15;
      int grow = row0 + r;
      u32x4 p = (u32x4){0, 0, 0, 0};
      if (grow < n) p = __builtin_nontemporal_load((const u32x4*)&Z[(long long)grow * 128 + kg8 * 8]);
      *(u32x4*)&T[r * KP + kg8 * 8] = p;
    }
    __syncthreads();

    // stage 1: rows [wv*16, wv*16+16): acc1 = Ztile @ W1
    f32x4 acc1[8];
#pragma unroll
    for (int nt = 0; nt < 8; ++nt) acc1[nt] = (f32x4){0.f, 0.f, 0.f, 0.f};
#pragma unroll
    for (int kc = 0; kc < 4; ++kc) {
      bf16x8 a = as_bf16x8(*(const uint4*)&T[(wv * 16 + l16) * KP + kc * 32 + lg * 8]);
#pragma unroll
      for (int nt = 0; nt < 8; ++nt) {
        bf16x8 b = as_bf16x8(*(const uint4*)&W1t[(nt * 16 + l16) * KP + kc * 32 + lg * 8]);
        acc1[nt] = __builtin_amdgcn_mfma_f32_16x16x32_bf16(a, b, acc1[nt], 0, 0, 0);
      }
    }
    __syncthreads();  // all waves' Ztile reads done before x1 overwrite
    // epilogue 1: x1 = relu(acc1 + b1) -> T (bf16), rows rb..rb+3, col nt*16+l16
#pragma unroll
    for (int reg = 0; reg < 4; ++reg) {
#pragma unroll
      for (int nt = 0; nt < 8; ++nt) {
        int c = nt * 16 + l16;
        T[(rb + reg) * KP + c] = bf16_1(fmaxf(acc1[nt][reg] + b1[c], 0.f));
      }
    }
    __syncthreads();  // x1 tile complete

    // stage 2: H2 rows [wv*16,+16) = dinv * (x1 @ W2)
    f32x4 acc2[4];
#pragma unroll
    for (int nt = 0; nt < 4; ++nt) acc2[nt] = (f32x4){0.f, 0.f, 0.f, 0.f};
#pragma unroll
    for (int kc = 0; kc < 4; ++kc) {
      bf16x8 a = as_bf16x8(*(const uint4*)&T[(wv * 16 + l16) * KP + kc * 32 + lg * 8]);
#pragma unroll
      for (int nt = 0; nt < 4; ++nt) {
        bf16x8 b = as_bf16x8(*(const uint4*)&W2t[(nt * 16 + l16) * KP + kc * 32 + lg * 8]);
        acc2[nt] = __builtin_amdgcn_mfma_f32_16x16x32_bf16(a, b, acc2[nt], 0, 0, 0);
      }
    }
#pragma unroll
    for (int reg = 0; reg < 4; ++reg) {
      int grow = row0 + rb + reg;
      if (grow < n) {
        float di = dinv[grow];
#pragma unroll
        for (int nt = 0; nt < 4; ++nt)
          H2[(long long)grow * 64 + nt * 16 + l16] = bf16_1(acc2[nt][reg] * di);  // reused: cached
      }
    }
  }
}

// ---------- k8: layer-2 aggregate (bf16 gathers, fp32 accumulate) -> fp32 out ----------
__global__ __launch_bounds__(256)
void agg2_k(const int* __restrict__ off, const int* __restrict__ ssrc,
            const uint4* __restrict__ HSv, const float* __restrict__ dinv,
            const float* __restrict__ bias, float* __restrict__ Y, int n) {
  constexpr int TPR = 8;    // 8 lanes x 16B = 128B row
  constexpr int RPB = 32;
  const int lane = threadIdx.x % TPR;
  const int r    = threadIdx.x / TPR;
  const int c8   = lane * 8;
  const float4 bb0 = *(const float4*)&bias[c8];
  const float4 bb1 = *(const float4*)&bias[c8 + 4];

  for (int d = blockIdx.x * RPB + r; d < n; d += gridDim.x * RPB) {
    int beg = off[d], end = off[d + 1];
    float acc[8];
    {
      uint4 g = HSv[(long long)d * TPR + lane];  // self-loop term
      acc[0] = bf_lo(g.x); acc[1] = bf_hi(g.x);
      acc[2] = bf_lo(g.y); acc[3] = bf_hi(g.y);
      acc[4] = bf_lo(g.z); acc[5] = bf_hi(g.z);
      acc[6] = bf_lo(g.w); acc[7] = bf_hi(g.w);
    }
    int e = beg;
    for (; e + 4 <= end; e += 4) {
      int s0 = __builtin_nontemporal_load(&ssrc[e]);
      int s1 = __builtin_nontemporal_load(&ssrc[e + 1]);
      int s2 = __builtin_nontemporal_load(&ssrc[e + 2]);
      int s3 = __builtin_nontemporal_load(&ssrc[e + 3]);
      uint4 g0 = HSv[(long long)s0 * TPR + lane];
      uint4 g1 = HSv[(long long)s1 * TPR + lane];
      uint4 g2 = HSv[(long long)s2 * TPR + lane];
      uint4 g3 = HSv[(long long)s3 * TPR + lane];
      acc[0] += (bf_lo(g0.x) + bf_lo(g1.x)) + (bf_lo(g2.x) + bf_lo(g3.x));
      acc[1] += (bf_hi(g0.x) + bf_hi(g1.x)) + (bf_hi(g2.x) + bf_hi(g3.x));
      acc[2] += (bf_lo(g0.y) + bf_lo(g1.y)) + (bf_lo(g2.y) + bf_lo(g3.y));
      acc[3] += (bf_hi(g0.y) + bf_hi(g1.y)) + (bf_hi(g2.y) + bf_hi(g3.y));
      acc[4] += (bf_lo(g0.z) + bf_lo(g1.z)) + (bf_lo(g2.z) + bf_lo(g3.z));
      acc[5] += (bf_hi(g0.z) + bf_hi(g1.z)) + (bf_hi(g2.z) + bf_hi(g3.z));
      acc[6] += (bf_lo(g0.w) + bf_lo(g1.w)) + (bf_lo(g2.w) + bf_lo(g3.w));
      acc[7] += (bf_hi(g0.w) + bf_hi(g1.w)) + (bf_hi(g2.w) + bf_hi(g3.w));
    }
    for (; e < end; ++e) {
      uint4 g = HSv[(long long)ssrc[e] * TPR + lane];
      acc[0] += bf_lo(g.x); acc[1] += bf_hi(g.x);
      acc[2] += bf_lo(g.y); acc[3] += bf_hi(g.y);
      acc[4] += bf_lo(g.z); acc[5] += bf_hi(g.z);
      acc[6] += bf_lo(g.w); acc[7] += bf_hi(g.w);
    }
    float di = dinv[d];
    f32x4 y0, y1;
    y0.x = fmaxf(fmaf(di, acc[0], bb0.x), 0.f);
    y0.y = fmaxf(fmaf(di, acc[1], bb0.y), 0.f);
    y0.z = fmaxf(fmaf(di, acc[2], bb0.z), 0.f);
    y0.w = fmaxf(fmaf(di, acc[3], bb0.w), 0.f);
    y1.x = fmaxf(fmaf(di, acc[4], bb1.x), 0.f);
    y1.y = fmaxf(fmaf(di, acc[5], bb1.y), 0.f);
    y1.z = fmaxf(fmaf(di, acc[6], bb1.z), 0.f);
    y1.w = fmaxf(fmaf(di, acc[7], bb1.w), 0.f);
    __builtin_nontemporal_store(y0, (f32x4*)&Y[(long long)d * 64 + c8]);      // write-once
    __builtin_nontemporal_store(y1, (f32x4*)&Y[(long long)d * 64 + c8 + 4]);  // don't evict H2
  }
}

extern "C" void kernel_launch(void* const* d_in, const int* in_sizes, int n_in,
                              void* d_out, int out_size, void* d_ws, size_t ws_size,
                              hipStream_t stream) {
  const float* x  = (const float*)d_in[0];
  const int*   ei = (const int*)d_in[1];
  const float* W1 = (const float*)d_in[2];
  const float* b1 = (const float*)d_in[3];
  const float* W2 = (const float*)d_in[4];
  const float* b2 = (const float*)d_in[5];
  float* out = (float*)d_out;

  const int n = in_sizes[0] / IN_DIM;   // 100000
  const int E = in_sizes[1] / 2;        // 1600000

  // workspace layout (bytes)
  char* ws = (char*)d_ws;
  size_t o = 0;
  auto alloc = [&](size_t bytes) { char* p = ws + o; o = (o + bytes + 255) & ~(size_t)255; return p; };
  float* dinv   = (float*)alloc((size_t)n * 4);
  int*   off    = (int*)  alloc((size_t)(n + 1) * 4);
  int*   btot   = (int*)  alloc((size_t)1024 * 4);
  int*   bkbase = (int*)  alloc((size_t)1025 * 4);
  int*   hist   = (int*)  alloc((size_t)G_SORT * 1024 * 4);  // 1 MB
  int*   ssrc   = (int*)  alloc((size_t)E * 4);
  unsigned short* xs = (unsigned short*)alloc((size_t)n * 128 * 2);  // bf16 x (25.6 MB)
  unsigned short* Z  = (unsigned short*)alloc((size_t)n * 128 * 2);  // bf16 A_hat@x (25.6 MB)
  unsigned short* H2 = (unsigned short*)alloc((size_t)n * 64 * 2);   // bf16 HS2 (12.8 MB)
  // ent (6.4 MB) overlays Z: live only fillc->fill2, before Z is written (aggx)
  unsigned* ent = (unsigned*)Z;

  const int NB = (n + (1 << BSHIFT) - 1) >> BSHIFT; // 782 buckets (<= 1024 required)
  const int ntiles = (n + 63) / 64;                 // 64-row tiles
  const long long nx8 = (long long)n * (IN_DIM / 8);

  // k1: hist (blocks 0..255) || x->bf16 convert (blocks 256..1279)
  hist_cvt_k<<<G_SORT + 1024, 256, 0, stream>>>(ei, E, NB, hist, x, xs, nx8);
  // k2..k5: counting-sort CSR build; off/dinv derived in-sort
  hsum_k<<<NB, G_SORT, 0, stream>>>(hist, NB, btot);
  bscan_k<<<1, 1024, 0, stream>>>(btot, NB, bkbase, off, n, E);
  fillc_k<<<G_SORT, 256, 0, stream>>>(ei, E, NB, hist, bkbase, ent);
  fill2_k<<<NB, 256, 0, stream>>>(bkbase, ent, ssrc, off, dinv, n);

  // k6: Z = A_hat @ x  (normalized aggregation of bf16 x)
  aggx_k<<<4096, 256, 0, stream>>>(off, ssrc, (const uint4*)xs, dinv, Z, n);

  // k7: H2 = dinv * (relu(Z@W1 + b1) @ W2)   (fused double matmul)
  mm12_k<<<782, 256, 0, stream>>>(Z, W1, b1, W2, dinv, H2, n, ntiles);

  // k8: out = relu(dinv*(H2_d + sum H2_s) + b2)
  agg2_k<<<4096, 256, 0, stream>>>(off, ssrc, (const uint4*)H2, dinv, b2, out, n);
}

// Round 15
// 180.017 us; speedup vs baseline: 1.1644x; 1.1644x over previous
//
#include <hip/hip_runtime.h>

constexpr int IN_DIM = 128;
constexpr int BSHIFT = 7;     // 128 nodes per bucket
constexpr int G_SORT = 256;   // blocks in the counting-sort passes
// NOTE: requires n <= 2^25 (src packs in 25 bits), n <= 1024<<BSHIFT (LDS hist),
// and NB <= 1024 (single-block bucket scan); n=100000 ok.

typedef float  f32x4  __attribute__((ext_vector_type(4)));
typedef short  bf16x8 __attribute__((ext_vector_type(8)));

// bf16 helpers: storage-only compression (accumulate in fp32)
__device__ inline unsigned pk_bf16(float a, float b) {  // RTNE pack of 2 floats
  unsigned ua = __float_as_uint(a), ub = __float_as_uint(b);
  ua += 0x7fff + ((ua >> 16) & 1);
  ub += 0x7fff + ((ub >> 16) & 1);
  return (ua >> 16) | (ub & 0xffff0000u);
}
__device__ inline unsigned short bf16_1(float a) {
  unsigned u = __float_as_uint(a);
  u += 0x7fff + ((u >> 16) & 1);
  return (unsigned short)(u >> 16);
}
__device__ inline float bf_lo(unsigned u) { return __uint_as_float(u << 16); }
__device__ inline float bf_hi(unsigned u) { return __uint_as_float(u & 0xffff0000u); }
__device__ inline bf16x8 as_bf16x8(uint4 v) { bf16x8 r; __builtin_memcpy(&r, &v, 16); return r; }

// ---------- k1: grid-fused {edge-bucket histogram | x fp32 -> bf16 convert} ----------
__global__ __launch_bounds__(256)
void hist_cvt_k(const int* __restrict__ ei, int E, int K, int* __restrict__ hist,
                const float* __restrict__ x, unsigned short* __restrict__ xs,
                long long nx8) {
  if (blockIdx.x < G_SORT) {
    __shared__ int lh[1024];
    for (int i = threadIdx.x; i < K; i += 256) lh[i] = 0;
    __syncthreads();
    int C = (E + G_SORT - 1) / G_SORT;
    int beg = blockIdx.x * C;
    int end = min(E, beg + C);
    for (int i = beg + threadIdx.x; i < end; i += 256)
      atomicAdd(&lh[ei[E + i] >> BSHIFT], 1);
    __syncthreads();
    for (int i = threadIdx.x; i < K; i += 256) hist[blockIdx.x * K + i] = lh[i];
  } else {
    long long t = (long long)(blockIdx.x - G_SORT) * 256 + threadIdx.x;
    long long stride = (long long)(gridDim.x - G_SORT) * 256;
    for (; t < nx8; t += stride) {
      const float* xp = &x[t * 8];
      float4 a = *(const float4*)xp;
      float4 b = *(const float4*)(xp + 4);
      uint4 p;
      p.x = pk_bf16(a.x, a.y); p.y = pk_bf16(a.z, a.w);
      p.z = pk_bf16(b.x, b.y); p.w = pk_bf16(b.z, b.w);
      *(uint4*)&xs[t * 8] = p;
    }
  }
}

// ---------- k2: column-scan hist over blocks; emit bucket totals ----------
__global__ __launch_bounds__(G_SORT)
void hsum_k(int* __restrict__ hist, int K, int* __restrict__ btot) {
  __shared__ int sd[G_SORT];
  int k = blockIdx.x;
  int v = hist[threadIdx.x * K + k];
  sd[threadIdx.x] = v;
  __syncthreads();
#pragma unroll
  for (int ofs = 1; ofs < G_SORT; ofs <<= 1) {
    int t = (threadIdx.x >= ofs) ? sd[threadIdx.x - ofs] : 0;
    __syncthreads();
    sd[threadIdx.x] += t;
    __syncthreads();
  }
  hist[threadIdx.x * K + k] = sd[threadIdx.x] - v;       // exclusive within bucket
  if (threadIdx.x == G_SORT - 1) btot[k] = sd[threadIdx.x];  // bucket total
}

// ---------- k3: single-block exclusive scan of bucket totals -> bkbase ----------
__global__ __launch_bounds__(1024)
void bscan_k(const int* __restrict__ btot, int NB, int* __restrict__ bkbase,
             int* __restrict__ off, int n, int E) {
  __shared__ int sd[1024];
  int v = (threadIdx.x < NB) ? btot[threadIdx.x] : 0;
  sd[threadIdx.x] = v;
  __syncthreads();
#pragma unroll
  for (int ofs = 1; ofs < 1024; ofs <<= 1) {
    int t = (threadIdx.x >= ofs) ? sd[threadIdx.x - ofs] : 0;
    __syncthreads();
    sd[threadIdx.x] += t;
    __syncthreads();
  }
  if (threadIdx.x < NB) bkbase[threadIdx.x] = sd[threadIdx.x] - v;  // exclusive
  if (threadIdx.x == 0) { bkbase[NB] = E; off[n] = E; }
}

// ---------- k4: place packed (d_local,src) at reserved positions ----------
__global__ __launch_bounds__(256)
void fillc_k(const int* __restrict__ ei, int E, int K, const int* __restrict__ hist,
             const int* __restrict__ bkbase, unsigned* __restrict__ ent) {
  __shared__ int lcur[1024];
  for (int i = threadIdx.x; i < K; i += 256)
    lcur[i] = bkbase[i] + hist[blockIdx.x * K + i];
  __syncthreads();
  int C = (E + gridDim.x - 1) / gridDim.x;
  int beg = blockIdx.x * C;
  int end = min(E, beg + C);
  for (int i = beg + threadIdx.x; i < end; i += 256) {
    int s = ei[i];
    int d = ei[E + i];
    int pos = atomicAdd(&lcur[d >> BSHIFT], 1);
    ent[pos] = ((unsigned)(d & ((1 << BSHIFT) - 1)) << 25) | (unsigned)s;
  }
}

// ---------- k5: per-bucket -> node-exact CSR; derive off/dinv as by-products ----------
__global__ __launch_bounds__(256)
void fill2_k(const int* __restrict__ bkbase, const unsigned* __restrict__ ent,
             int* __restrict__ ssrc, int* __restrict__ off, float* __restrict__ dinv,
             int n) {
  constexpr int BK = 1 << BSHIFT;  // 128
  __shared__ int lcnt[BK];
  __shared__ int lbase[BK];
  __shared__ int sd[BK];
  const int tid = threadIdx.x;
  int node0 = blockIdx.x << BSHIFT;
  int nn = min(BK, n - node0);
  int beg = bkbase[blockIdx.x], end = bkbase[blockIdx.x + 1];

  if (tid < BK) lcnt[tid] = 0;
  __syncthreads();
  for (int i = beg + tid; i < end; i += 256)
    atomicAdd(&lcnt[ent[i] >> 25], 1);
  __syncthreads();
  int v = (tid < BK) ? lcnt[tid] : 0;
  if (tid < BK) sd[tid] = v;
  __syncthreads();
#pragma unroll
  for (int ofs = 1; ofs < BK; ofs <<= 1) {
    int t = 0;
    if (tid < BK && tid >= ofs) t = sd[tid - ofs];
    __syncthreads();
    if (tid < BK) sd[tid] += t;
    __syncthreads();
  }
  if (tid < BK) {
    int base = beg + sd[tid] - v;
    lbase[tid] = base;
    lcnt[tid] = 0;
    if (tid < nn) {
      off[node0 + tid] = base;
      dinv[node0 + tid] = rsqrtf((float)v + 1.0f);  // +1 self-loop
    }
  }
  __syncthreads();
  for (int i = beg + tid; i < end; i += 256) {
    unsigned p = ent[i];
    int dl = (int)(p >> 25);
    int s  = (int)(p & ((1u << 25) - 1));
    int pos = lbase[dl] + atomicAdd(&lcnt[dl], 1);
    ssrc[pos] = s;
  }
}

// ---------- k6: normalized input aggregation ----------
// Z[d] = bf16( dinv_d * ( dinv_d*xs[d] + sum_e dinv_{s_e}*xs[s_e] ) )   [= row of A_hat @ x]
__global__ __launch_bounds__(256)
void aggx_k(const int* __restrict__ off, const int* __restrict__ ssrc,
            const uint4* __restrict__ XSv, const float* __restrict__ dinv,
            unsigned short* __restrict__ Z, int n) {
  constexpr int TPR = 16;   // 16 lanes x 16B = 256B row
  constexpr int RPB = 16;
  const int lane = threadIdx.x & 15;
  const int r    = threadIdx.x >> 4;
  const int c8   = lane * 8;

  for (int d = blockIdx.x * RPB + r; d < n; d += gridDim.x * RPB) {
    int beg = off[d], end = off[d + 1];
    float dd = dinv[d];
    float acc[8];
    {
      uint4 g = XSv[(long long)d * TPR + lane];  // self-loop term * dinv_d
      acc[0] = dd * bf_lo(g.x); acc[1] = dd * bf_hi(g.x);
      acc[2] = dd * bf_lo(g.y); acc[3] = dd * bf_hi(g.y);
      acc[4] = dd * bf_lo(g.z); acc[5] = dd * bf_hi(g.z);
      acc[6] = dd * bf_lo(g.w); acc[7] = dd * bf_hi(g.w);
    }
    int e = beg;
    for (; e + 4 <= end; e += 4) {  // 4 independent gathers in flight
      int s0 = ssrc[e], s1 = ssrc[e + 1], s2 = ssrc[e + 2], s3 = ssrc[e + 3];
      float w0 = dinv[s0], w1 = dinv[s1], w2 = dinv[s2], w3 = dinv[s3];
      uint4 g0 = XSv[(long long)s0 * TPR + lane];
      uint4 g1 = XSv[(long long)s1 * TPR + lane];
      uint4 g2 = XSv[(long long)s2 * TPR + lane];
      uint4 g3 = XSv[(long long)s3 * TPR + lane];
      acc[0] += w0 * bf_lo(g0.x) + w1 * bf_lo(g1.x) + w2 * bf_lo(g2.x) + w3 * bf_lo(g3.x);
      acc[1] += w0 * bf_hi(g0.x) + w1 * bf_hi(g1.x) + w2 * bf_hi(g2.x) + w3 * bf_hi(g3.x);
      acc[2] += w0 * bf_lo(g0.y) + w1 * bf_lo(g1.y) + w2 * bf_lo(g2.y) + w3 * bf_lo(g3.y);
      acc[3] += w0 * bf_hi(g0.y) + w1 * bf_hi(g1.y) + w2 * bf_hi(g2.y) + w3 * bf_hi(g3.y);
      acc[4] += w0 * bf_lo(g0.z) + w1 * bf_lo(g1.z) + w2 * bf_lo(g2.z) + w3 * bf_lo(g3.z);
      acc[5] += w0 * bf_hi(g0.z) + w1 * bf_hi(g1.z) + w2 * bf_hi(g2.z) + w3 * bf_hi(g3.z);
      acc[6] += w0 * bf_lo(g0.w) + w1 * bf_lo(g1.w) + w2 * bf_lo(g2.w) + w3 * bf_lo(g3.w);
      acc[7] += w0 * bf_hi(g0.w) + w1 * bf_hi(g1.w) + w2 * bf_hi(g2.w) + w3 * bf_hi(g3.w);
    }
    for (; e < end; ++e) {
      int s = ssrc[e];
      float w = dinv[s];
      uint4 g = XSv[(long long)s * TPR + lane];
      acc[0] += w * bf_lo(g.x); acc[1] += w * bf_hi(g.x);
      acc[2] += w * bf_lo(g.y); acc[3] += w * bf_hi(g.y);
      acc[4] += w * bf_lo(g.z); acc[5] += w * bf_hi(g.z);
      acc[6] += w * bf_lo(g.w); acc[7] += w * bf_hi(g.w);
    }
    uint4 p;
    p.x = pk_bf16(dd * acc[0], dd * acc[1]);
    p.y = pk_bf16(dd * acc[2], dd * acc[3]);
    p.z = pk_bf16(dd * acc[4], dd * acc[5]);
    p.w = pk_bf16(dd * acc[6], dd * acc[7]);
    *(uint4*)&Z[(long long)d * 128 + c8] = p;
  }
}

// ---------- k7: fused double matmul ----------
// per 64-row tile: x1 = relu(Z @ W1 + b1) (LDS, bf16); H2 = dinv * (x1 @ W2) (bf16 out)
__global__ __launch_bounds__(256)
void mm12_k(const unsigned short* __restrict__ Z, const float* __restrict__ W1,
            const float* __restrict__ b1, const float* __restrict__ W2,
            const float* __restrict__ dinv, unsigned short* __restrict__ H2,
            int n, int ntiles) {
  constexpr int KP = 136;  // padded K row stride in bf16 (272B)
  __shared__ unsigned short W1t[128 * KP];  // 34.8 KB  W1^T: [c][k]
  __shared__ unsigned short W2t[64 * KP];   // 17.4 KB  W2^T: [c][k]
  __shared__ unsigned short T[64 * KP];     // 17.4 KB  Z tile, then x1 tile

  const int tid = threadIdx.x;
  for (int i = tid; i < 128 * 128; i += 256) {
    int k = i >> 7, c = i & 127;
    W1t[c * KP + k] = bf16_1(W1[i]);
  }
  for (int i = tid; i < 128 * 64; i += 256) {
    int k = i / 64, c = i % 64;
    W2t[c * KP + k] = bf16_1(W2[i]);
  }
  const int wv = tid >> 6, l = tid & 63, l16 = l & 15, lg = l >> 4;
  const int rb = wv * 16 + lg * 4;

  for (int t = blockIdx.x; t < ntiles; t += gridDim.x) {
    int row0 = t * 64;
    __syncthreads();  // W staging (first iter) / prev-tile readers done
    for (int i = tid; i < 64 * 16; i += 256) {
      int r = i >> 4, kg8 = i & 15;
      int grow = row0 + r;
      uint4 p = make_uint4(0, 0, 0, 0);
      if (grow < n) p = *(const uint4*)&Z[(long long)grow * 128 + kg8 * 8];
      *(uint4*)&T[r * KP + kg8 * 8] = p;
    }
    __syncthreads();

    // stage 1: rows [wv*16, wv*16+16): acc1 = Ztile @ W1
    f32x4 acc1[8];
#pragma unroll
    for (int nt = 0; nt < 8; ++nt) acc1[nt] = (f32x4){0.f, 0.f, 0.f, 0.f};
#pragma unroll
    for (int kc = 0; kc < 4; ++kc) {
      bf16x8 a = as_bf16x8(*(const uint4*)&T[(wv * 16 + l16) * KP + kc * 32 + lg * 8]);
#pragma unroll
      for (int nt = 0; nt < 8; ++nt) {
        bf16x8 b = as_bf16x8(*(const uint4*)&W1t[(nt * 16 + l16) * KP + kc * 32 + lg * 8]);
        acc1[nt] = __builtin_amdgcn_mfma_f32_16x16x32_bf16(a, b, acc1[nt], 0, 0, 0);
      }
    }
    __syncthreads();  // all waves' Ztile reads done before x1 overwrite
    // epilogue 1: x1 = relu(acc1 + b1) -> T (bf16), rows rb..rb+3, col nt*16+l16
#pragma unroll
    for (int reg = 0; reg < 4; ++reg) {
#pragma unroll
      for (int nt = 0; nt < 8; ++nt) {
        int c = nt * 16 + l16;
        T[(rb + reg) * KP + c] = bf16_1(fmaxf(acc1[nt][reg] + b1[c], 0.f));
      }
    }
    __syncthreads();  // x1 tile complete

    // stage 2: H2 rows [wv*16,+16) = dinv * (x1 @ W2)
    f32x4 acc2[4];
#pragma unroll
    for (int nt = 0; nt < 4; ++nt) acc2[nt] = (f32x4){0.f, 0.f, 0.f, 0.f};
#pragma unroll
    for (int kc = 0; kc < 4; ++kc) {
      bf16x8 a = as_bf16x8(*(const uint4*)&T[(wv * 16 + l16) * KP + kc * 32 + lg * 8]);
#pragma unroll
      for (int nt = 0; nt < 4; ++nt) {
        bf16x8 b = as_bf16x8(*(const uint4*)&W2t[(nt * 16 + l16) * KP + kc * 32 + lg * 8]);
        acc2[nt] = __builtin_amdgcn_mfma_f32_16x16x32_bf16(a, b, acc2[nt], 0, 0, 0);
      }
    }
#pragma unroll
    for (int reg = 0; reg < 4; ++reg) {
      int grow = row0 + rb + reg;
      if (grow < n) {
        float di = dinv[grow];
#pragma unroll
        for (int nt = 0; nt < 4; ++nt)
          H2[(long long)grow * 64 + nt * 16 + l16] = bf16_1(acc2[nt][reg] * di);
      }
    }
  }
}

// ---------- k8: layer-2 aggregate (bf16 gathers, fp32 accumulate) -> fp32 out ----------
__global__ __launch_bounds__(256)
void agg2_k(const int* __restrict__ off, const int* __restrict__ ssrc,
            const uint4* __restrict__ HSv, const float* __restrict__ dinv,
            const float* __restrict__ bias, float* __restrict__ Y, int n) {
  constexpr int TPR = 8;    // 8 lanes x 16B = 128B row
  constexpr int RPB = 32;
  const int lane = threadIdx.x % TPR;
  const int r    = threadIdx.x / TPR;
  const int c8   = lane * 8;
  const float4 bb0 = *(const float4*)&bias[c8];
  const float4 bb1 = *(const float4*)&bias[c8 + 4];

  for (int d = blockIdx.x * RPB + r; d < n; d += gridDim.x * RPB) {
    int beg = off[d], end = off[d + 1];
    float acc[8];
    {
      uint4 g = HSv[(long long)d * TPR + lane];  // self-loop term
      acc[0] = bf_lo(g.x); acc[1] = bf_hi(g.x);
      acc[2] = bf_lo(g.y); acc[3] = bf_hi(g.y);
      acc[4] = bf_lo(g.z); acc[5] = bf_hi(g.z);
      acc[6] = bf_lo(g.w); acc[7] = bf_hi(g.w);
    }
    int e = beg;
    for (; e + 4 <= end; e += 4) {
      int s0 = ssrc[e], s1 = ssrc[e + 1], s2 = ssrc[e + 2], s3 = ssrc[e + 3];
      uint4 g0 = HSv[(long long)s0 * TPR + lane];
      uint4 g1 = HSv[(long long)s1 * TPR + lane];
      uint4 g2 = HSv[(long long)s2 * TPR + lane];
      uint4 g3 = HSv[(long long)s3 * TPR + lane];
      acc[0] += (bf_lo(g0.x) + bf_lo(g1.x)) + (bf_lo(g2.x) + bf_lo(g3.x));
      acc[1] += (bf_hi(g0.x) + bf_hi(g1.x)) + (bf_hi(g2.x) + bf_hi(g3.x));
      acc[2] += (bf_lo(g0.y) + bf_lo(g1.y)) + (bf_lo(g2.y) + bf_lo(g3.y));
      acc[3] += (bf_hi(g0.y) + bf_hi(g1.y)) + (bf_hi(g2.y) + bf_hi(g3.y));
      acc[4] += (bf_lo(g0.z) + bf_lo(g1.z)) + (bf_lo(g2.z) + bf_lo(g3.z));
      acc[5] += (bf_hi(g0.z) + bf_hi(g1.z)) + (bf_hi(g2.z) + bf_hi(g3.z));
      acc[6] += (bf_lo(g0.w) + bf_lo(g1.w)) + (bf_lo(g2.w) + bf_lo(g3.w));
      acc[7] += (bf_hi(g0.w) + bf_hi(g1.w)) + (bf_hi(g2.w) + bf_hi(g3.w));
    }
    for (; e < end; ++e) {
      uint4 g = HSv[(long long)ssrc[e] * TPR + lane];
      acc[0] += bf_lo(g.x); acc[1] += bf_hi(g.x);
      acc[2] += bf_lo(g.y); acc[3] += bf_hi(g.y);
      acc[4] += bf_lo(g.z); acc[5] += bf_hi(g.z);
      acc[6] += bf_lo(g.w); acc[7] += bf_hi(g.w);
    }
    float di = dinv[d];
    float4 y0, y1;
    y0.x = fmaxf(fmaf(di, acc[0], bb0.x), 0.f);
    y0.y = fmaxf(fmaf(di, acc[1], bb0.y), 0.f);
    y0.z = fmaxf(fmaf(di, acc[2], bb0.z), 0.f);
    y0.w = fmaxf(fmaf(di, acc[3], bb0.w), 0.f);
    y1.x = fmaxf(fmaf(di, acc[4], bb1.x), 0.f);
    y1.y = fmaxf(fmaf(di, acc[5], bb1.y), 0.f);
    y1.z = fmaxf(fmaf(di, acc[6], bb1.z), 0.f);
    y1.w = fmaxf(fmaf(di, acc[7], bb1.w), 0.f);
    *(float4*)&Y[(long long)d * 64 + c8]     = y0;
    *(float4*)&Y[(long long)d * 64 + c8 + 4] = y1;
  }
}

extern "C" void kernel_launch(void* const* d_in, const int* in_sizes, int n_in,
                              void* d_out, int out_size, void* d_ws, size_t ws_size,
                              hipStream_t stream) {
  const float* x  = (const float*)d_in[0];
  const int*   ei = (const int*)d_in[1];
  const float* W1 = (const float*)d_in[2];
  const float* b1 = (const float*)d_in[3];
  const float* W2 = (const float*)d_in[4];
  const float* b2 = (const float*)d_in[5];
  float* out = (float*)d_out;

  const int n = in_sizes[0] / IN_DIM;   // 100000
  const int E = in_sizes[1] / 2;        // 1600000

  // workspace layout (bytes)
  char* ws = (char*)d_ws;
  size_t o = 0;
  auto alloc = [&](size_t bytes) { char* p = ws + o; o = (o + bytes + 255) & ~(size_t)255; return p; };
  float* dinv   = (float*)alloc((size_t)n * 4);
  int*   off    = (int*)  alloc((size_t)(n + 1) * 4);
  int*   btot   = (int*)  alloc((size_t)1024 * 4);
  int*   bkbase = (int*)  alloc((size_t)1025 * 4);
  int*   hist   = (int*)  alloc((size_t)G_SORT * 1024 * 4);  // 1 MB
  int*   ssrc   = (int*)  alloc((size_t)E * 4);
  unsigned short* xs = (unsigned short*)alloc((size_t)n * 128 * 2);  // bf16 x (25.6 MB)
  unsigned short* Z  = (unsigned short*)alloc((size_t)n * 128 * 2);  // bf16 A_hat@x (25.6 MB)
  unsigned short* H2 = (unsigned short*)alloc((size_t)n * 64 * 2);   // bf16 HS2 (12.8 MB)
  // ent (6.4 MB) overlays Z: live only fillc->fill2, before Z is written (aggx)
  unsigned* ent = (unsigned*)Z;

  const int NB = (n + (1 << BSHIFT) - 1) >> BSHIFT; // 782 buckets (<= 1024 required)
  const int ntiles = (n + 63) / 64;                 // 64-row tiles
  const long long nx8 = (long long)n * (IN_DIM / 8);

  // k1: hist (blocks 0..255) || x->bf16 convert (blocks 256..1279)
  hist_cvt_k<<<G_SORT + 1024, 256, 0, stream>>>(ei, E, NB, hist, x, xs, nx8);
  // k2..k5: counting-sort CSR build; off/dinv derived in-sort
  hsum_k<<<NB, G_SORT, 0, stream>>>(hist, NB, btot);
  bscan_k<<<1, 1024, 0, stream>>>(btot, NB, bkbase, off, n, E);
  fillc_k<<<G_SORT, 256, 0, stream>>>(ei, E, NB, hist, bkbase, ent);
  fill2_k<<<NB, 256, 0, stream>>>(bkbase, ent, ssrc, off, dinv, n);

  // k6: Z = A_hat @ x  (normalized aggregation of bf16 x)
  aggx_k<<<4096, 256, 0, stream>>>(off, ssrc, (const uint4*)xs, dinv, Z, n);

  // k7: H2 = dinv * (relu(Z@W1 + b1) @ W2)   (fused double matmul)
  mm12_k<<<782, 256, 0, stream>>>(Z, W1, b1, W2, dinv, H2, n, ntiles);

  // k8: out = relu(dinv*(H2_d + sum H2_s) + b2)
  agg2_k<<<4096, 256, 0, stream>>>(off, ssrc, (const uint4*)H2, dinv, b2, out, n);
}